// Round 8
// baseline (719.938 us; speedup 1.0000x reference)
//
#include <hip/hip_runtime.h>

static inline int idiv(int a, int b) { return (a + b - 1) / b; }

// ---------------- zero region via kernel ----------------
__global__ void k_zero(float4* __restrict__ p, long n4) {
    long t = (long)blockIdx.x * blockDim.x + threadIdx.x;
    long stride = (long)gridDim.x * blockDim.x;
    for (; t < n4; t += stride) p[t] = make_float4(0.f, 0.f, 0.f, 0.f);
}

// ---------------- histogram: cnt[dst[e]]++ ----------------
__global__ void k_hist(const int* __restrict__ dst, int* __restrict__ cnt, int E) {
    int t = blockIdx.x * blockDim.x + threadIdx.x;
    if (t < E) atomicAdd(&cnt[dst[t]], 1);
}

// ---------------- dinv[i] = cnt>0 ? cnt^-0.5 : 0 ----------------
__global__ void k_dinv(const int* __restrict__ cnt, float* __restrict__ dinv, int n) {
    int t = blockIdx.x * blockDim.x + threadIdx.x;
    if (t < n) {
        int c = cnt[t];
        dinv[t] = (c > 0) ? rsqrtf((float)c) : 0.0f;
    }
}

// ---- single-block hierarchical exclusive scan: offs & cursor from cnt ----
__global__ void k_scan(const int* __restrict__ cnt, int* __restrict__ offs,
                       int* __restrict__ cursor, int n) {
    __shared__ int part[1024];
    int tid = threadIdx.x;
    int chunk = (n + 1023) / 1024;
    int lo = tid * chunk, hi = lo + chunk;
    if (hi > n) hi = n;
    int s = 0;
    for (int i = lo; i < hi; i++) s += cnt[i];
    part[tid] = s;
    __syncthreads();
    // Hillis-Steele inclusive scan over 1024 partials
    for (int off = 1; off < 1024; off <<= 1) {
        int v = (tid >= off) ? part[tid - off] : 0;
        __syncthreads();
        part[tid] += v;
        __syncthreads();
    }
    int run = (tid == 0) ? 0 : part[tid - 1];
    for (int i = lo; i < hi; i++) {
        offs[i] = run;
        cursor[i] = run;
        run += cnt[i];
    }
}

// ---------------- fill CSR: csr[cursor[dst[e]]++] = src[e] ----------------
__global__ void k_fill(const int* __restrict__ src, const int* __restrict__ dst,
                       int* __restrict__ cursor, int* __restrict__ csr, int E) {
    int t = blockIdx.x * blockDim.x + threadIdx.x;
    if (t < E) {
        int pos = atomicAdd(&cursor[dst[t]], 1);
        csr[pos] = src[t];
    }
}

// ---- gather: tx[d][f] = -dinv[d] * sum_{s in N(d)} dinv[s]*x[s][f] ----
template <int LOGF>
__global__ void k_gather(const int* __restrict__ offs, const int* __restrict__ cnt,
                         const int* __restrict__ csr, const float* __restrict__ dinv,
                         const float* __restrict__ xin, float* __restrict__ tx, int n) {
    int t = blockIdx.x * blockDim.x + threadIdx.x;
    int d = t >> LOGF, f = t & ((1 << LOGF) - 1);
    if (d >= n) return;
    int beg = offs[d], num = cnt[d];
    float acc = 0.0f;
    for (int i = 0; i < num; i++) {
        int s = csr[beg + i];
        acc += dinv[s] * xin[((long)s << LOGF) + f];
    }
    tx[((long)d << LOGF) + f] = -dinv[d] * acc;
}

// ---- layer1 fused: val = relu(x@W0 + tx@W1 + b); hp[cl[n]][j] max= val ----
__global__ void k_cheb1_max(const float* __restrict__ x, const float* __restrict__ tx,
                            const float* __restrict__ W0, const float* __restrict__ W1,
                            const float* __restrict__ b, const int* __restrict__ cl,
                            float* __restrict__ hp, int N) {
    __shared__ float sW0[16 * 32], sW1[16 * 32], sb[32];
    for (int i = threadIdx.x; i < 16 * 32; i += blockDim.x) {
        sW0[i] = W0[i];
        sW1[i] = W1[i];
    }
    if (threadIdx.x < 32) sb[threadIdx.x] = b[threadIdx.x];
    __syncthreads();
    int t = blockIdx.x * blockDim.x + threadIdx.x;
    int n = t >> 5, j = t & 31;
    if (n >= N) return;
    const float* xr = x + (long)n * 16;
    const float* tr = tx + (long)n * 16;
    float acc = sb[j];
#pragma unroll
    for (int k = 0; k < 16; k++) acc += xr[k] * sW0[k * 32 + j] + tr[k] * sW1[k * 32 + j];
    float v = fmaxf(acc, 0.0f);  // >= 0, so int-punned atomicMax on zero-init is exact
    atomicMax((int*)&hp[((long)cl[n] << 5) + j], __float_as_int(v));
}

// ---- layer2 fused: val = relu(hp@W0 + tx@W1 + b); h3[cl[n]][j] max= val ----
__global__ void k_cheb2_max(const float* __restrict__ xp, const float* __restrict__ tx,
                            const float* __restrict__ W0, const float* __restrict__ W1,
                            const float* __restrict__ b, const int* __restrict__ cl,
                            float* __restrict__ h3, int n1) {
    __shared__ float sW0[32 * 64], sW1[32 * 64], sb[64];
    for (int i = threadIdx.x; i < 32 * 64; i += blockDim.x) {
        sW0[i] = W0[i];
        sW1[i] = W1[i];
    }
    if (threadIdx.x < 64) sb[threadIdx.x] = b[threadIdx.x];
    __syncthreads();
    int t = blockIdx.x * blockDim.x + threadIdx.x;
    int n = t >> 6, j = t & 63;
    if (n >= n1) return;
    const float* xr = xp + (long)n * 32;
    const float* tr = tx + (long)n * 32;
    float acc = sb[j];
#pragma unroll
    for (int k = 0; k < 32; k++) acc += xr[k] * sW0[k * 64 + j] + tr[k] * sW1[k * 64 + j];
    float v = fmaxf(acc, 0.0f);
    atomicMax((int*)&h3[((long)cl[n] << 6) + j], __float_as_int(v));
}

// ---- per-graph sum + count: two-stage (LDS partials -> one atomic set per block) ----
__global__ void k_gsum(const float* __restrict__ h3, const int* __restrict__ batch,
                       float* __restrict__ gsum, float* __restrict__ gcnt, int n2) {
    __shared__ float s[8 * 64];
    __shared__ float sc[8];
    for (int i = threadIdx.x; i < 512; i += blockDim.x) s[i] = 0.0f;
    if (threadIdx.x < 8) sc[threadIdx.x] = 0.0f;
    __syncthreads();
    long total = (long)n2 * 64;
    long stride = (long)gridDim.x * blockDim.x;
    for (long t = (long)blockIdx.x * blockDim.x + threadIdx.x; t < total; t += stride) {
        int n = (int)(t >> 6), f = (int)(t & 63);
        int g = batch[n];
        atomicAdd(&s[g * 64 + f], h3[t]);
        if (f == 0) atomicAdd(&sc[g], 1.0f);
    }
    __syncthreads();
    for (int i = threadIdx.x; i < 512; i += blockDim.x) atomicAdd(&gsum[i], s[i]);
    if (threadIdx.x < 8) atomicAdd(&gcnt[threadIdx.x], sc[threadIdx.x]);
}

// ---------------- fc1: g1 = relu(mean @ fcw1 + fcb1), one block ----------------
__global__ void k_fc1(const float* __restrict__ gsum, const float* __restrict__ gcnt,
                      const float* __restrict__ fcw1, const float* __restrict__ fcb1,
                      float* __restrict__ g1) {
    __shared__ float sg[8 * 64];
    int tid = threadIdx.x;
    if (tid < 512) {
        float c = gcnt[tid >> 6];
        sg[tid] = (c > 0.0f) ? gsum[tid] / c : 0.0f;
    }
    __syncthreads();
    int gi = tid >> 7, j = tid & 127;
    float acc = fcb1[j];
#pragma unroll 8
    for (int k = 0; k < 64; k++) acc += sg[gi * 64 + k] * fcw1[k * 128 + j];
    g1[tid] = fmaxf(acc, 0.0f);
}

// ---------------- fc2: out = g1 @ fcw2 + fcb2, f32 output ----------------
__global__ void k_fc2(const float* __restrict__ g1, const float* __restrict__ fcw2,
                      const float* __restrict__ fcb2, float* __restrict__ out, int OUT) {
    __shared__ float sg[8 * 128];
    for (int i = threadIdx.x; i < 1024; i += blockDim.x) sg[i] = g1[i];
    __syncthreads();
    int o = blockIdx.x * blockDim.x + threadIdx.x;
    if (o >= OUT) return;
    float bias = fcb2[o];
    float acc[8];
#pragma unroll
    for (int gi = 0; gi < 8; gi++) acc[gi] = bias;
    for (int k = 0; k < 128; k++) {
        float w = fcw2[(long)k * OUT + o];
#pragma unroll
        for (int gi = 0; gi < 8; gi++) acc[gi] += sg[gi * 128 + k] * w;
    }
#pragma unroll
    for (int gi = 0; gi < 8; gi++) out[(long)gi * OUT + o] = acc[gi];
}

extern "C" void kernel_launch(void* const* d_in, const int* in_sizes, int n_in,
                              void* d_out, int out_size, void* d_ws, size_t ws_size,
                              hipStream_t stream) {
    const float* x    = (const float*)d_in[0];
    const float* W0a  = (const float*)d_in[1];
    const float* W1a  = (const float*)d_in[2];
    const float* b1   = (const float*)d_in[3];
    const float* W0b  = (const float*)d_in[4];
    const float* W1b  = (const float*)d_in[5];
    const float* b2   = (const float*)d_in[6];
    const float* fcw1 = (const float*)d_in[7];
    const float* fcb1 = (const float*)d_in[8];
    const float* fcw2 = (const float*)d_in[9];
    const float* fcb2 = (const float*)d_in[10];
    const int* ei1    = (const int*)d_in[11];
    const int* cl1    = (const int*)d_in[12];
    const int* ei2    = (const int*)d_in[13];
    const int* cl2    = (const int*)d_in[14];
    const int* b3     = (const int*)d_in[15];

    const int N  = in_sizes[12];        // len(cluster1) = 80000
    const int E1 = in_sizes[11] / 2;
    const int E2 = in_sizes[13] / 2;
    const int n1 = in_sizes[14];        // len(cluster2)
    const int n2 = in_sizes[15];        // len(batch3)
    const int G  = 8;
    const int OUT = out_size / G;       // 20000

    const int nmax = (N > n1) ? N : n1;
    const int Emax = (E1 > E2) ? E1 : E2;

    // ---- workspace layout: [zeroed: cnt | hp | h3 | small] [offs | cursor | csr | dinv | txA]
    auto rnd = [](size_t b) { return (b + 255) & ~(size_t)255; };
    size_t cntB  = rnd((size_t)nmax * 4);
    size_t hpB   = rnd((size_t)n1 * 32 * 4);
    size_t h3B   = rnd((size_t)n2 * 64 * 4);
    size_t smlB  = rnd((512 + 8 + 1024) * 4);
    size_t offB  = rnd((size_t)nmax * 4);
    size_t curB  = rnd((size_t)nmax * 4);
    size_t csrB  = rnd((size_t)Emax * 4);
    size_t dinvB = rnd((size_t)nmax * 4);
    size_t txB   = rnd((size_t)(((long)N * 16 > (long)n1 * 32) ? (long)N * 16 : (long)n1 * 32) * 4);

    char* base = (char*)d_ws;
    int*   cnt    = (int*)base;
    float* hp     = (float*)(base + cntB);
    float* h3     = (float*)(base + cntB + hpB);
    float* gsum   = (float*)(base + cntB + hpB + h3B);
    float* gcnt   = gsum + 512;
    float* g1     = gcnt + 8;
    size_t zeroB  = cntB + hpB + h3B + smlB;
    int*   offs   = (int*)(base + zeroB);
    int*   cursor = (int*)(base + zeroB + offB);
    int*   csr    = (int*)(base + zeroB + offB + curB);
    float* dinv   = (float*)(base + zeroB + offB + curB + csrB);
    float* txA    = (float*)(base + zeroB + offB + curB + csrB + dinvB);
    (void)txB; (void)ws_size;

    dim3 B(256);
    // ---- zero the accumulator regions (cnt, hp, h3, gsum/gcnt/g1) ----
    {
        long n4 = (long)(zeroB / 16);
        int g = idiv((int)((n4 < 1048576) ? n4 : 1048576), 256);
        if (g < 1) g = 1;
        if (g > 4096) g = 4096;
        k_zero<<<g, B, 0, stream>>>((float4*)base, n4);
    }

    // ---- layer 1: CSR build + gather + fused cheb/pool ----
    k_hist<<<idiv(E1, 256), B, 0, stream>>>(ei1 + E1, cnt, E1);
    k_dinv<<<idiv(N, 256), B, 0, stream>>>(cnt, dinv, N);
    k_scan<<<1, 1024, 0, stream>>>(cnt, offs, cursor, N);
    k_fill<<<idiv(E1, 256), B, 0, stream>>>(ei1, ei1 + E1, cursor, csr, E1);
    k_gather<4><<<idiv(N * 16, 256), B, 0, stream>>>(offs, cnt, csr, dinv, x, txA, N);
    k_cheb1_max<<<idiv(N * 32, 256), B, 0, stream>>>(x, txA, W0a, W1a, b1, cl1, hp, N);

    // ---- re-zero cnt for layer 2 ----
    {
        long n4 = (long)(cntB / 16);
        int g = idiv((int)n4, 256);
        if (g < 1) g = 1;
        if (g > 4096) g = 4096;
        k_zero<<<g, B, 0, stream>>>((float4*)cnt, n4);
    }

    // ---- layer 2 ----
    k_hist<<<idiv(E2, 256), B, 0, stream>>>(ei2 + E2, cnt, E2);
    k_dinv<<<idiv(n1, 256), B, 0, stream>>>(cnt, dinv, n1);
    k_scan<<<1, 1024, 0, stream>>>(cnt, offs, cursor, n1);
    k_fill<<<idiv(E2, 256), B, 0, stream>>>(ei2, ei2 + E2, cursor, csr, E2);
    k_gather<5><<<idiv(n1 * 32, 256), B, 0, stream>>>(offs, cnt, csr, dinv, hp, txA, n1);
    k_cheb2_max<<<idiv(n1 * 64, 256), B, 0, stream>>>(hp, txA, W0b, W1b, b2, cl2, h3, n1);

    // ---- readout ----
    int gb = idiv(n2 * 64, 256);
    if (gb > 256) gb = 256;
    k_gsum<<<gb, B, 0, stream>>>(h3, b3, gsum, gcnt, n2);
    k_fc1<<<1, 1024, 0, stream>>>(gsum, gcnt, fcw1, fcb1, g1);
    k_fc2<<<idiv(OUT, 256), B, 0, stream>>>(g1, fcw2, fcb2, (float*)d_out, OUT);
}

// Round 9
// 477.048 us; speedup vs baseline: 1.5092x; 1.5092x over previous
//
#include <hip/hip_runtime.h>

static inline int idiv(int a, int b) { return (a + b - 1) / b; }

// ---------------- zero region via kernel ----------------
__global__ void k_zero(float4* __restrict__ p, long n4) {
    long t = (long)blockIdx.x * blockDim.x + threadIdx.x;
    long stride = (long)gridDim.x * blockDim.x;
    for (; t < n4; t += stride) p[t] = make_float4(0.f, 0.f, 0.f, 0.f);
}

// ---------------- histogram: cnt[dst[e]]++ ----------------
__global__ void k_hist(const int* __restrict__ dst, int* __restrict__ cnt, int E) {
    int t = blockIdx.x * blockDim.x + threadIdx.x;
    if (t < E) atomicAdd(&cnt[dst[t]], 1);
}

// ---------------- dinv[i] = cnt>0 ? cnt^-0.5 : 0 ----------------
__global__ void k_dinv(const int* __restrict__ cnt, float* __restrict__ dinv, int n) {
    int t = blockIdx.x * blockDim.x + threadIdx.x;
    if (t < n) {
        int c = cnt[t];
        dinv[t] = (c > 0) ? rsqrtf((float)c) : 0.0f;
    }
}

// ---- scan phase 1: per-block (1024 elems) exclusive prefixes + block total ----
__global__ void k_scan_blk(const int* __restrict__ cnt, int* __restrict__ offs,
                           int* __restrict__ blksum, int n) {
    __shared__ int ts[256];
    int blk = blockIdx.x;
    int tid = threadIdx.x;
    int i0 = blk * 1024 + tid * 4;
    int a0 = 0, a1 = 0, a2 = 0, a3 = 0;
    if (i0 + 3 < n) {
        int4 v = *(const int4*)&cnt[i0];
        a0 = v.x; a1 = v.y; a2 = v.z; a3 = v.w;
    } else {
        if (i0 + 0 < n) a0 = cnt[i0 + 0];
        if (i0 + 1 < n) a1 = cnt[i0 + 1];
        if (i0 + 2 < n) a2 = cnt[i0 + 2];
    }
    int tsum = a0 + a1 + a2 + a3;
    ts[tid] = tsum;
    __syncthreads();
    for (int off = 1; off < 256; off <<= 1) {
        int v = (tid >= off) ? ts[tid - off] : 0;
        __syncthreads();
        ts[tid] += v;
        __syncthreads();
    }
    int ex = ts[tid] - tsum;  // exclusive prefix of this thread within block
    if (tid == 255) blksum[blk] = ts[255];
    int p0 = ex, p1 = ex + a0, p2 = p1 + a1, p3 = p2 + a2;
    if (i0 + 3 < n) {
        *(int4*)&offs[i0] = make_int4(p0, p1, p2, p3);
    } else {
        if (i0 + 0 < n) offs[i0 + 0] = p0;
        if (i0 + 1 < n) offs[i0 + 1] = p1;
        if (i0 + 2 < n) offs[i0 + 2] = p2;
    }
}

// ---- scan phase 2: exclusive scan of block totals (single block, nblk <= 1024) ----
__global__ void k_scan_tot(int* __restrict__ blksum, int nblk) {
    __shared__ int s[1024];
    int tid = threadIdx.x;
    int v = (tid < nblk) ? blksum[tid] : 0;
    s[tid] = v;
    __syncthreads();
    for (int off = 1; off < 1024; off <<= 1) {
        int t = (tid >= off) ? s[tid - off] : 0;
        __syncthreads();
        s[tid] += t;
        __syncthreads();
    }
    if (tid < nblk) blksum[tid] = s[tid] - v;  // exclusive
}

// ---- scan phase 3: add block offsets; produce offs and cursor ----
__global__ void k_scan_add(int* __restrict__ offs, int* __restrict__ cursor,
                           const int* __restrict__ blksum, int n) {
    int t = blockIdx.x * blockDim.x + threadIdx.x;
    if (t < n) {
        int v = offs[t] + blksum[t >> 10];
        offs[t] = v;
        cursor[t] = v;
    }
}

// ---------------- fill CSR: csr[cursor[dst[e]]++] = src[e] ----------------
__global__ void k_fill(const int* __restrict__ src, const int* __restrict__ dst,
                       int* __restrict__ cursor, int* __restrict__ csr, int E) {
    int t = blockIdx.x * blockDim.x + threadIdx.x;
    if (t < E) {
        int pos = atomicAdd(&cursor[dst[t]], 1);
        csr[pos] = src[t];
    }
}

// ---- gather: tx[d][f] = -dinv[d] * sum_{s in N(d)} dinv[s]*x[s][f] ----
template <int LOGF>
__global__ void k_gather(const int* __restrict__ offs, const int* __restrict__ cnt,
                         const int* __restrict__ csr, const float* __restrict__ dinv,
                         const float* __restrict__ xin, float* __restrict__ tx, int n) {
    int t = blockIdx.x * blockDim.x + threadIdx.x;
    int d = t >> LOGF, f = t & ((1 << LOGF) - 1);
    if (d >= n) return;
    int beg = offs[d], num = cnt[d];
    float acc = 0.0f;
    for (int i = 0; i < num; i++) {
        int s = csr[beg + i];
        acc += dinv[s] * xin[((long)s << LOGF) + f];
    }
    tx[((long)d << LOGF) + f] = -dinv[d] * acc;
}

// ---- layer1 fused: val = relu(x@W0 + tx@W1 + b); hp[cl[n]][j] max= val ----
__global__ void k_cheb1_max(const float* __restrict__ x, const float* __restrict__ tx,
                            const float* __restrict__ W0, const float* __restrict__ W1,
                            const float* __restrict__ b, const int* __restrict__ cl,
                            float* __restrict__ hp, int N) {
    __shared__ float sW0[16 * 32], sW1[16 * 32], sb[32];
    for (int i = threadIdx.x; i < 16 * 32; i += blockDim.x) {
        sW0[i] = W0[i];
        sW1[i] = W1[i];
    }
    if (threadIdx.x < 32) sb[threadIdx.x] = b[threadIdx.x];
    __syncthreads();
    int t = blockIdx.x * blockDim.x + threadIdx.x;
    int n = t >> 5, j = t & 31;
    if (n >= N) return;
    const float* xr = x + (long)n * 16;
    const float* tr = tx + (long)n * 16;
    float acc = sb[j];
#pragma unroll
    for (int k = 0; k < 16; k++) acc += xr[k] * sW0[k * 32 + j] + tr[k] * sW1[k * 32 + j];
    float v = fmaxf(acc, 0.0f);  // >= 0, so int-punned atomicMax on zero-init is exact
    atomicMax((int*)&hp[((long)cl[n] << 5) + j], __float_as_int(v));
}

// ---- layer2 fused: val = relu(hp@W0 + tx@W1 + b); h3[cl[n]][j] max= val ----
__global__ void k_cheb2_max(const float* __restrict__ xp, const float* __restrict__ tx,
                            const float* __restrict__ W0, const float* __restrict__ W1,
                            const float* __restrict__ b, const int* __restrict__ cl,
                            float* __restrict__ h3, int n1) {
    __shared__ float sW0[32 * 64], sW1[32 * 64], sb[64];
    for (int i = threadIdx.x; i < 32 * 64; i += blockDim.x) {
        sW0[i] = W0[i];
        sW1[i] = W1[i];
    }
    if (threadIdx.x < 64) sb[threadIdx.x] = b[threadIdx.x];
    __syncthreads();
    int t = blockIdx.x * blockDim.x + threadIdx.x;
    int n = t >> 6, j = t & 63;
    if (n >= n1) return;
    const float* xr = xp + (long)n * 32;
    const float* tr = tx + (long)n * 32;
    float acc = sb[j];
#pragma unroll
    for (int k = 0; k < 32; k++) acc += xr[k] * sW0[k * 64 + j] + tr[k] * sW1[k * 64 + j];
    float v = fmaxf(acc, 0.0f);
    atomicMax((int*)&h3[((long)cl[n] << 6) + j], __float_as_int(v));
}

// ---- per-graph sum + count: two-stage (LDS partials -> one atomic set per block) ----
__global__ void k_gsum(const float* __restrict__ h3, const int* __restrict__ batch,
                       float* __restrict__ gsum, float* __restrict__ gcnt, int n2) {
    __shared__ float s[8 * 64];
    __shared__ float sc[8];
    for (int i = threadIdx.x; i < 512; i += blockDim.x) s[i] = 0.0f;
    if (threadIdx.x < 8) sc[threadIdx.x] = 0.0f;
    __syncthreads();
    long total = (long)n2 * 64;
    long stride = (long)gridDim.x * blockDim.x;
    for (long t = (long)blockIdx.x * blockDim.x + threadIdx.x; t < total; t += stride) {
        int n = (int)(t >> 6), f = (int)(t & 63);
        int g = batch[n];
        atomicAdd(&s[g * 64 + f], h3[t]);
        if (f == 0) atomicAdd(&sc[g], 1.0f);
    }
    __syncthreads();
    for (int i = threadIdx.x; i < 512; i += blockDim.x) atomicAdd(&gsum[i], s[i]);
    if (threadIdx.x < 8) atomicAdd(&gcnt[threadIdx.x], sc[threadIdx.x]);
}

// ---------------- fc1: g1 = relu(mean @ fcw1 + fcb1), one block ----------------
__global__ void k_fc1(const float* __restrict__ gsum, const float* __restrict__ gcnt,
                      const float* __restrict__ fcw1, const float* __restrict__ fcb1,
                      float* __restrict__ g1) {
    __shared__ float sg[8 * 64];
    int tid = threadIdx.x;
    if (tid < 512) {
        float c = gcnt[tid >> 6];
        sg[tid] = (c > 0.0f) ? gsum[tid] / c : 0.0f;
    }
    __syncthreads();
    int gi = tid >> 7, j = tid & 127;
    float acc = fcb1[j];
#pragma unroll 8
    for (int k = 0; k < 64; k++) acc += sg[gi * 64 + k] * fcw1[k * 128 + j];
    g1[tid] = fmaxf(acc, 0.0f);
}

// ---------------- fc2: out = g1 @ fcw2 + fcb2, f32 output ----------------
__global__ void k_fc2(const float* __restrict__ g1, const float* __restrict__ fcw2,
                      const float* __restrict__ fcb2, float* __restrict__ out, int OUT) {
    __shared__ float sg[8 * 128];
    for (int i = threadIdx.x; i < 1024; i += blockDim.x) sg[i] = g1[i];
    __syncthreads();
    int o = blockIdx.x * blockDim.x + threadIdx.x;
    if (o >= OUT) return;
    float bias = fcb2[o];
    float acc[8];
#pragma unroll
    for (int gi = 0; gi < 8; gi++) acc[gi] = bias;
    for (int k = 0; k < 128; k++) {
        float w = fcw2[(long)k * OUT + o];
#pragma unroll
        for (int gi = 0; gi < 8; gi++) acc[gi] += sg[gi * 128 + k] * w;
    }
#pragma unroll
    for (int gi = 0; gi < 8; gi++) out[(long)gi * OUT + o] = acc[gi];
}

extern "C" void kernel_launch(void* const* d_in, const int* in_sizes, int n_in,
                              void* d_out, int out_size, void* d_ws, size_t ws_size,
                              hipStream_t stream) {
    const float* x    = (const float*)d_in[0];
    const float* W0a  = (const float*)d_in[1];
    const float* W1a  = (const float*)d_in[2];
    const float* b1   = (const float*)d_in[3];
    const float* W0b  = (const float*)d_in[4];
    const float* W1b  = (const float*)d_in[5];
    const float* b2   = (const float*)d_in[6];
    const float* fcw1 = (const float*)d_in[7];
    const float* fcb1 = (const float*)d_in[8];
    const float* fcw2 = (const float*)d_in[9];
    const float* fcb2 = (const float*)d_in[10];
    const int* ei1    = (const int*)d_in[11];
    const int* cl1    = (const int*)d_in[12];
    const int* ei2    = (const int*)d_in[13];
    const int* cl2    = (const int*)d_in[14];
    const int* b3     = (const int*)d_in[15];

    const int N  = in_sizes[12];        // len(cluster1) = 80000
    const int E1 = in_sizes[11] / 2;
    const int E2 = in_sizes[13] / 2;
    const int n1 = in_sizes[14];        // len(cluster2)
    const int n2 = in_sizes[15];        // len(batch3)
    const int G  = 8;
    const int OUT = out_size / G;       // 20000

    const int nmax = (N > n1) ? N : n1;
    const int Emax = (E1 > E2) ? E1 : E2;

    // ---- workspace layout: [zeroed: cnt | hp | h3 | small] [offs | cursor | csr | dinv | blksum | txA]
    auto rnd = [](size_t b) { return (b + 255) & ~(size_t)255; };
    size_t cntB  = rnd((size_t)nmax * 4);
    size_t hpB   = rnd((size_t)n1 * 32 * 4);
    size_t h3B   = rnd((size_t)n2 * 64 * 4);
    size_t smlB  = rnd((512 + 8 + 1024) * 4);
    size_t offB  = rnd((size_t)nmax * 4);
    size_t curB  = rnd((size_t)nmax * 4);
    size_t csrB  = rnd((size_t)Emax * 4);
    size_t dinvB = rnd((size_t)nmax * 4);
    size_t blkB  = rnd((size_t)1024 * 4);

    char* base = (char*)d_ws;
    int*   cnt    = (int*)base;
    float* hp     = (float*)(base + cntB);
    float* h3     = (float*)(base + cntB + hpB);
    float* gsum   = (float*)(base + cntB + hpB + h3B);
    float* gcnt   = gsum + 512;
    float* g1     = gcnt + 8;
    size_t zeroB  = cntB + hpB + h3B + smlB;
    int*   offs   = (int*)(base + zeroB);
    int*   cursor = (int*)(base + zeroB + offB);
    int*   csr    = (int*)(base + zeroB + offB + curB);
    float* dinv   = (float*)(base + zeroB + offB + curB + csrB);
    int*   blksum = (int*)(base + zeroB + offB + curB + csrB + dinvB);
    float* txA    = (float*)(base + zeroB + offB + curB + csrB + dinvB + blkB);
    (void)ws_size;

    dim3 B(256);
    // ---- zero the accumulator regions (cnt, hp, h3, gsum/gcnt/g1) ----
    {
        long n4 = (long)(zeroB / 16);
        int g = idiv((int)((n4 < 1048576) ? n4 : 1048576), 256);
        if (g < 1) g = 1;
        if (g > 4096) g = 4096;
        k_zero<<<g, B, 0, stream>>>((float4*)base, n4);
    }

    // ---- layer 1: CSR build + gather + fused cheb/pool ----
    {
        int nblk = idiv(N, 1024);
        k_hist<<<idiv(E1, 256), B, 0, stream>>>(ei1 + E1, cnt, E1);
        k_dinv<<<idiv(N, 256), B, 0, stream>>>(cnt, dinv, N);
        k_scan_blk<<<nblk, B, 0, stream>>>(cnt, offs, blksum, N);
        k_scan_tot<<<1, 1024, 0, stream>>>(blksum, nblk);
        k_scan_add<<<idiv(N, 256), B, 0, stream>>>(offs, cursor, blksum, N);
        k_fill<<<idiv(E1, 256), B, 0, stream>>>(ei1, ei1 + E1, cursor, csr, E1);
        k_gather<4><<<idiv(N * 16, 256), B, 0, stream>>>(offs, cnt, csr, dinv, x, txA, N);
        k_cheb1_max<<<idiv(N * 32, 256), B, 0, stream>>>(x, txA, W0a, W1a, b1, cl1, hp, N);
    }

    // ---- re-zero cnt for layer 2 ----
    {
        long n4 = (long)(cntB / 16);
        int g = idiv((int)n4, 256);
        if (g < 1) g = 1;
        if (g > 4096) g = 4096;
        k_zero<<<g, B, 0, stream>>>((float4*)cnt, n4);
    }

    // ---- layer 2 ----
    {
        int nblk = idiv(n1, 1024);
        k_hist<<<idiv(E2, 256), B, 0, stream>>>(ei2 + E2, cnt, E2);
        k_dinv<<<idiv(n1, 256), B, 0, stream>>>(cnt, dinv, n1);
        k_scan_blk<<<nblk, B, 0, stream>>>(cnt, offs, blksum, n1);
        k_scan_tot<<<1, 1024, 0, stream>>>(blksum, nblk);
        k_scan_add<<<idiv(n1, 256), B, 0, stream>>>(offs, cursor, blksum, n1);
        k_fill<<<idiv(E2, 256), B, 0, stream>>>(ei2, ei2 + E2, cursor, csr, E2);
        k_gather<5><<<idiv(n1 * 32, 256), B, 0, stream>>>(offs, cnt, csr, dinv, hp, txA, n1);
        k_cheb2_max<<<idiv(n1 * 64, 256), B, 0, stream>>>(hp, txA, W0b, W1b, b2, cl2, h3, n1);
    }

    // ---- readout ----
    int gb = idiv(n2 * 64, 256);
    if (gb > 256) gb = 256;
    k_gsum<<<gb, B, 0, stream>>>(h3, b3, gsum, gcnt, n2);
    k_fc1<<<1, 1024, 0, stream>>>(gsum, gcnt, fcw1, fcb1, g1);
    k_fc2<<<idiv(OUT, 256), B, 0, stream>>>(g1, fcw2, fcb2, (float*)d_out, OUT);
}

// Round 10
// 276.192 us; speedup vs baseline: 2.6067x; 1.7272x over previous
//
#include <hip/hip_runtime.h>

static inline int idiv(int a, int b) { return (a + b - 1) / b; }

// ---------------- zero region via kernel ----------------
__global__ void k_zero(float4* __restrict__ p, long n4) {
    long t = (long)blockIdx.x * blockDim.x + threadIdx.x;
    long stride = (long)gridDim.x * blockDim.x;
    for (; t < n4; t += stride) p[t] = make_float4(0.f, 0.f, 0.f, 0.f);
}

// ---- layer1 bounds: up-edge (src<dst) runs are contiguous & sorted by src ----
__global__ void k_bounds1(const int* __restrict__ src, const int* __restrict__ dst,
                          int* __restrict__ ust, int* __restrict__ uen, int E) {
    int e = blockIdx.x * blockDim.x + threadIdx.x;
    if (e >= E) return;
    int s = src[e], d = dst[e];
    if (s >= d) return;  // only up-edges
    bool prevup = false; int ps = -1;
    if (e > 0) { ps = src[e - 1]; prevup = (ps < dst[e - 1]); }
    if (e == 0 || !prevup || ps != s) ust[s] = e;
    bool nextup = false; int ns = -1;
    if (e + 1 < E) { ns = src[e + 1]; nextup = (ns < dst[e + 1]); }
    if (e + 1 == E || !nextup || ns != s) uen[s] = e + 1;
}

// ---- layer2 bounds: src2 globally sorted; runs give full neighbor lists ----
__global__ void k_bounds2(const int* __restrict__ src, int* __restrict__ rs,
                          int* __restrict__ re, int E) {
    int e = blockIdx.x * blockDim.x + threadIdx.x;
    if (e >= E) return;
    int s = src[e];
    if (e == 0 || src[e - 1] != s) rs[s] = e;
    if (e + 1 == E || src[e + 1] != s) re[s] = e + 1;
}

// ---- histogram of smaller-neighbor counts: up-edges keyed by dst ----
__global__ void k_histS(const int* __restrict__ src, const int* __restrict__ dst,
                        int* __restrict__ cntS, int E) {
    int e = blockIdx.x * blockDim.x + threadIdx.x;
    if (e >= E) return;
    int s = src[e], d = dst[e];
    if (s < d) atomicAdd(&cntS[d], 1);
}

// ---- dinv layer1: deg = cntS + up-run length ----
__global__ void k_dinv1(const int* __restrict__ cntS, const int* __restrict__ ust,
                        const int* __restrict__ uen, float* __restrict__ dinv, int n) {
    int t = blockIdx.x * blockDim.x + threadIdx.x;
    if (t < n) {
        int deg = cntS[t] + uen[t] - ust[t];
        dinv[t] = (deg > 0) ? rsqrtf((float)deg) : 0.0f;
    }
}

// ---- dinv layer2: deg = run length ----
__global__ void k_dinv2(const int* __restrict__ rs, const int* __restrict__ re,
                        float* __restrict__ dinv, int n) {
    int t = blockIdx.x * blockDim.x + threadIdx.x;
    if (t < n) {
        int deg = re[t] - rs[t];
        dinv[t] = (deg > 0) ? rsqrtf((float)deg) : 0.0f;
    }
}

// ---- scan phase 1: per-block (1024 elems) exclusive prefixes + block total ----
__global__ void k_scan_blk(const int* __restrict__ cnt, int* __restrict__ offs,
                           int* __restrict__ blksum, int n) {
    __shared__ int ts[256];
    int blk = blockIdx.x;
    int tid = threadIdx.x;
    int i0 = blk * 1024 + tid * 4;
    int a0 = 0, a1 = 0, a2 = 0, a3 = 0;
    if (i0 + 3 < n) {
        int4 v = *(const int4*)&cnt[i0];
        a0 = v.x; a1 = v.y; a2 = v.z; a3 = v.w;
    } else {
        if (i0 + 0 < n) a0 = cnt[i0 + 0];
        if (i0 + 1 < n) a1 = cnt[i0 + 1];
        if (i0 + 2 < n) a2 = cnt[i0 + 2];
    }
    int tsum = a0 + a1 + a2 + a3;
    ts[tid] = tsum;
    __syncthreads();
    for (int off = 1; off < 256; off <<= 1) {
        int v = (tid >= off) ? ts[tid - off] : 0;
        __syncthreads();
        ts[tid] += v;
        __syncthreads();
    }
    int ex = ts[tid] - tsum;
    if (tid == 255) blksum[blk] = ts[255];
    int p0 = ex, p1 = ex + a0, p2 = p1 + a1, p3 = p2 + a2;
    if (i0 + 3 < n) {
        *(int4*)&offs[i0] = make_int4(p0, p1, p2, p3);
    } else {
        if (i0 + 0 < n) offs[i0 + 0] = p0;
        if (i0 + 1 < n) offs[i0 + 1] = p1;
        if (i0 + 2 < n) offs[i0 + 2] = p2;
    }
}

// ---- scan phase 2: exclusive scan of block totals ----
__global__ void k_scan_tot(int* __restrict__ blksum, int nblk) {
    __shared__ int s[1024];
    int tid = threadIdx.x;
    int v = (tid < nblk) ? blksum[tid] : 0;
    s[tid] = v;
    __syncthreads();
    for (int off = 1; off < 1024; off <<= 1) {
        int t = (tid >= off) ? s[tid - off] : 0;
        __syncthreads();
        s[tid] += t;
        __syncthreads();
    }
    if (tid < nblk) blksum[tid] = s[tid] - v;
}

// ---- scan phase 3: add block offsets; produce offs and cursor ----
__global__ void k_scan_add(int* __restrict__ offs, int* __restrict__ cursor,
                           const int* __restrict__ blksum, int n) {
    int t = blockIdx.x * blockDim.x + threadIdx.x;
    if (t < n) {
        int v = offs[t] + blksum[t >> 10];
        offs[t] = v;
        cursor[t] = v;
    }
}

// ---- fill small-CSR: only up-edges, keyed by larger endpoint ----
__global__ void k_fillS(const int* __restrict__ src, const int* __restrict__ dst,
                        int* __restrict__ cursor, int* __restrict__ csr, int E) {
    int e = blockIdx.x * blockDim.x + threadIdx.x;
    if (e >= E) return;
    int s = src[e], d = dst[e];
    if (s < d) {
        int pos = atomicAdd(&cursor[d], 1);
        csr[pos] = s;
    }
}

// ---- gather1: larger nbrs from up-run of dst array + smaller nbrs from csrS ----
template <int LOGF>
__global__ void k_gather1(const int* __restrict__ ust, const int* __restrict__ uen,
                          const int* __restrict__ dst1, const int* __restrict__ offsS,
                          const int* __restrict__ cntS, const int* __restrict__ csrS,
                          const float* __restrict__ dinv, const float* __restrict__ xin,
                          float* __restrict__ tx, int n) {
    int t = blockIdx.x * blockDim.x + threadIdx.x;
    int d = t >> LOGF, f = t & ((1 << LOGF) - 1);
    if (d >= n) return;
    float acc = 0.0f;
    int e0 = ust[d], e1 = uen[d];
    for (int e = e0; e < e1; e++) {
        int s = dst1[e];
        acc += dinv[s] * xin[((long)s << LOGF) + f];
    }
    int b0 = offsS[d], c = cntS[d];
    for (int i = 0; i < c; i++) {
        int s = csrS[b0 + i];
        acc += dinv[s] * xin[((long)s << LOGF) + f];
    }
    tx[((long)d << LOGF) + f] = -dinv[d] * acc;
}

// ---- gather2: full neighbor list from sorted-src run ----
template <int LOGF>
__global__ void k_gather2(const int* __restrict__ rs, const int* __restrict__ re,
                          const int* __restrict__ dst2, const float* __restrict__ dinv,
                          const float* __restrict__ xin, float* __restrict__ tx, int n) {
    int t = blockIdx.x * blockDim.x + threadIdx.x;
    int d = t >> LOGF, f = t & ((1 << LOGF) - 1);
    if (d >= n) return;
    float acc = 0.0f;
    int j0 = rs[d], j1 = re[d];
    for (int j = j0; j < j1; j++) {
        int s = dst2[j];
        acc += dinv[s] * xin[((long)s << LOGF) + f];
    }
    tx[((long)d << LOGF) + f] = -dinv[d] * acc;
}

// ---- layer1 fused: val = relu(x@W0 + tx@W1 + b); hp[cl[n]][j] max= val ----
__global__ void k_cheb1_max(const float* __restrict__ x, const float* __restrict__ tx,
                            const float* __restrict__ W0, const float* __restrict__ W1,
                            const float* __restrict__ b, const int* __restrict__ cl,
                            float* __restrict__ hp, int N) {
    __shared__ float sW0[16 * 32], sW1[16 * 32], sb[32];
    for (int i = threadIdx.x; i < 16 * 32; i += blockDim.x) {
        sW0[i] = W0[i];
        sW1[i] = W1[i];
    }
    if (threadIdx.x < 32) sb[threadIdx.x] = b[threadIdx.x];
    __syncthreads();
    int t = blockIdx.x * blockDim.x + threadIdx.x;
    int n = t >> 5, j = t & 31;
    if (n >= N) return;
    const float* xr = x + (long)n * 16;
    const float* tr = tx + (long)n * 16;
    float acc = sb[j];
#pragma unroll
    for (int k = 0; k < 16; k++) acc += xr[k] * sW0[k * 32 + j] + tr[k] * sW1[k * 32 + j];
    float v = fmaxf(acc, 0.0f);  // >= 0, so int-punned atomicMax on zero-init is exact
    atomicMax((int*)&hp[((long)cl[n] << 5) + j], __float_as_int(v));
}

// ---- layer2 fused: val = relu(hp@W0 + tx@W1 + b); h3[cl[n]][j] max= val ----
__global__ void k_cheb2_max(const float* __restrict__ xp, const float* __restrict__ tx,
                            const float* __restrict__ W0, const float* __restrict__ W1,
                            const float* __restrict__ b, const int* __restrict__ cl,
                            float* __restrict__ h3, int n1) {
    __shared__ float sW0[32 * 64], sW1[32 * 64], sb[64];
    for (int i = threadIdx.x; i < 32 * 64; i += blockDim.x) {
        sW0[i] = W0[i];
        sW1[i] = W1[i];
    }
    if (threadIdx.x < 64) sb[threadIdx.x] = b[threadIdx.x];
    __syncthreads();
    int t = blockIdx.x * blockDim.x + threadIdx.x;
    int n = t >> 6, j = t & 63;
    if (n >= n1) return;
    const float* xr = xp + (long)n * 32;
    const float* tr = tx + (long)n * 32;
    float acc = sb[j];
#pragma unroll
    for (int k = 0; k < 32; k++) acc += xr[k] * sW0[k * 64 + j] + tr[k] * sW1[k * 64 + j];
    float v = fmaxf(acc, 0.0f);
    atomicMax((int*)&h3[((long)cl[n] << 6) + j], __float_as_int(v));
}

// ---- per-graph sum + count: two-stage ----
__global__ void k_gsum(const float* __restrict__ h3, const int* __restrict__ batch,
                       float* __restrict__ gsum, float* __restrict__ gcnt, int n2) {
    __shared__ float s[8 * 64];
    __shared__ float sc[8];
    for (int i = threadIdx.x; i < 512; i += blockDim.x) s[i] = 0.0f;
    if (threadIdx.x < 8) sc[threadIdx.x] = 0.0f;
    __syncthreads();
    long total = (long)n2 * 64;
    long stride = (long)gridDim.x * blockDim.x;
    for (long t = (long)blockIdx.x * blockDim.x + threadIdx.x; t < total; t += stride) {
        int n = (int)(t >> 6), f = (int)(t & 63);
        int g = batch[n];
        atomicAdd(&s[g * 64 + f], h3[t]);
        if (f == 0) atomicAdd(&sc[g], 1.0f);
    }
    __syncthreads();
    for (int i = threadIdx.x; i < 512; i += blockDim.x) atomicAdd(&gsum[i], s[i]);
    if (threadIdx.x < 8) atomicAdd(&gcnt[threadIdx.x], sc[threadIdx.x]);
}

// ---------------- fc1 ----------------
__global__ void k_fc1(const float* __restrict__ gsum, const float* __restrict__ gcnt,
                      const float* __restrict__ fcw1, const float* __restrict__ fcb1,
                      float* __restrict__ g1) {
    __shared__ float sg[8 * 64];
    int tid = threadIdx.x;
    if (tid < 512) {
        float c = gcnt[tid >> 6];
        sg[tid] = (c > 0.0f) ? gsum[tid] / c : 0.0f;
    }
    __syncthreads();
    int gi = tid >> 7, j = tid & 127;
    float acc = fcb1[j];
#pragma unroll 8
    for (int k = 0; k < 64; k++) acc += sg[gi * 64 + k] * fcw1[k * 128 + j];
    g1[tid] = fmaxf(acc, 0.0f);
}

// ---------------- fc2 ----------------
__global__ void k_fc2(const float* __restrict__ g1, const float* __restrict__ fcw2,
                      const float* __restrict__ fcb2, float* __restrict__ out, int OUT) {
    __shared__ float sg[8 * 128];
    for (int i = threadIdx.x; i < 1024; i += blockDim.x) sg[i] = g1[i];
    __syncthreads();
    int o = blockIdx.x * blockDim.x + threadIdx.x;
    if (o >= OUT) return;
    float bias = fcb2[o];
    float acc[8];
#pragma unroll
    for (int gi = 0; gi < 8; gi++) acc[gi] = bias;
    for (int k = 0; k < 128; k++) {
        float w = fcw2[(long)k * OUT + o];
#pragma unroll
        for (int gi = 0; gi < 8; gi++) acc[gi] += sg[gi * 128 + k] * w;
    }
#pragma unroll
    for (int gi = 0; gi < 8; gi++) out[(long)gi * OUT + o] = acc[gi];
}

extern "C" void kernel_launch(void* const* d_in, const int* in_sizes, int n_in,
                              void* d_out, int out_size, void* d_ws, size_t ws_size,
                              hipStream_t stream) {
    const float* x    = (const float*)d_in[0];
    const float* W0a  = (const float*)d_in[1];
    const float* W1a  = (const float*)d_in[2];
    const float* b1   = (const float*)d_in[3];
    const float* W0b  = (const float*)d_in[4];
    const float* W1b  = (const float*)d_in[5];
    const float* b2   = (const float*)d_in[6];
    const float* fcw1 = (const float*)d_in[7];
    const float* fcb1 = (const float*)d_in[8];
    const float* fcw2 = (const float*)d_in[9];
    const float* fcb2 = (const float*)d_in[10];
    const int* ei1    = (const int*)d_in[11];
    const int* cl1    = (const int*)d_in[12];
    const int* ei2    = (const int*)d_in[13];
    const int* cl2    = (const int*)d_in[14];
    const int* b3     = (const int*)d_in[15];

    const int N  = in_sizes[12];        // 80000
    const int E1 = in_sizes[11] / 2;
    const int E2 = in_sizes[13] / 2;
    const int n1 = in_sizes[14];
    const int n2 = in_sizes[15];
    const int G  = 8;
    const int OUT = out_size / G;       // 20000

    const int nmax = (N > n1) ? N : n1;

    // ---- workspace: [zeroed: cntS|ust|uen|rs2|re2|hp|h3|small] [offsS|cursorS|csrS|dinv|blksum|txA]
    auto rnd = [](size_t b) { return (b + 255) & ~(size_t)255; };
    size_t cntB  = rnd((size_t)N * 4);
    size_t ustB  = rnd((size_t)N * 4);
    size_t uenB  = rnd((size_t)N * 4);
    size_t rs2B  = rnd((size_t)n1 * 4);
    size_t re2B  = rnd((size_t)n1 * 4);
    size_t hpB   = rnd((size_t)n1 * 32 * 4);
    size_t h3B   = rnd((size_t)n2 * 64 * 4);
    size_t smlB  = rnd((512 + 8 + 1024) * 4);
    size_t offB  = rnd((size_t)N * 4);
    size_t curB  = rnd((size_t)N * 4);
    size_t csrB  = rnd((size_t)(E1 / 2 + 64) * 4);
    size_t dinvB = rnd((size_t)nmax * 4);
    size_t blkB  = rnd((size_t)1024 * 4);

    char* base = (char*)d_ws;
    char* p = base;
    int*   cntS   = (int*)p;           p += cntB;
    int*   ust    = (int*)p;           p += ustB;
    int*   uen    = (int*)p;           p += uenB;
    int*   rs2    = (int*)p;           p += rs2B;
    int*   re2    = (int*)p;           p += re2B;
    float* hp     = (float*)p;         p += hpB;
    float* h3     = (float*)p;         p += h3B;
    float* gsum   = (float*)p;         p += smlB;
    float* gcnt   = gsum + 512;
    float* g1     = gcnt + 8;
    size_t zeroB  = (size_t)(p - base);
    int*   offsS  = (int*)p;           p += offB;
    int*   cursorS= (int*)p;           p += curB;
    int*   csrS   = (int*)p;           p += csrB;
    float* dinv   = (float*)p;         p += dinvB;
    int*   blksum = (int*)p;           p += blkB;
    float* txA    = (float*)p;
    (void)ws_size;

    dim3 B(256);
    // ---- zero accumulator/bounds regions ----
    {
        long n4 = (long)(zeroB / 16);
        int g = idiv((int)((n4 < 1048576) ? n4 : 1048576), 256);
        if (g < 1) g = 1;
        if (g > 4096) g = 4096;
        k_zero<<<g, B, 0, stream>>>((float4*)base, n4);
    }

    // ---- layer 1 ----
    {
        int nblk = idiv(N, 1024);
        k_bounds1<<<idiv(E1, 256), B, 0, stream>>>(ei1, ei1 + E1, ust, uen, E1);
        k_histS<<<idiv(E1, 256), B, 0, stream>>>(ei1, ei1 + E1, cntS, E1);
        k_dinv1<<<idiv(N, 256), B, 0, stream>>>(cntS, ust, uen, dinv, N);
        k_scan_blk<<<nblk, B, 0, stream>>>(cntS, offsS, blksum, N);
        k_scan_tot<<<1, 1024, 0, stream>>>(blksum, nblk);
        k_scan_add<<<idiv(N, 256), B, 0, stream>>>(offsS, cursorS, blksum, N);
        k_fillS<<<idiv(E1, 256), B, 0, stream>>>(ei1, ei1 + E1, cursorS, csrS, E1);
        k_gather1<4><<<idiv(N * 16, 256), B, 0, stream>>>(ust, uen, ei1 + E1, offsS, cntS, csrS,
                                                          dinv, x, txA, N);
        k_cheb1_max<<<idiv(N * 32, 256), B, 0, stream>>>(x, txA, W0a, W1a, b1, cl1, hp, N);
    }

    // ---- layer 2: sorted src2 -> no CSR at all ----
    {
        k_bounds2<<<idiv(E2, 256), B, 0, stream>>>(ei2, rs2, re2, E2);
        k_dinv2<<<idiv(n1, 256), B, 0, stream>>>(rs2, re2, dinv, n1);
        k_gather2<5><<<idiv(n1 * 32, 256), B, 0, stream>>>(rs2, re2, ei2 + E2, dinv, hp, txA, n1);
        k_cheb2_max<<<idiv(n1 * 64, 256), B, 0, stream>>>(hp, txA, W0b, W1b, b2, cl2, h3, n1);
    }

    // ---- readout ----
    int gb = idiv(n2 * 64, 256);
    if (gb > 256) gb = 256;
    k_gsum<<<gb, B, 0, stream>>>(h3, b3, gsum, gcnt, n2);
    k_fc1<<<1, 1024, 0, stream>>>(gsum, gcnt, fcw1, fcb1, g1);
    k_fc2<<<idiv(OUT, 256), B, 0, stream>>>(g1, fcw2, fcb2, (float*)d_out, OUT);
}

// Round 11
// 221.991 us; speedup vs baseline: 3.2431x; 1.2442x over previous
//
#include <hip/hip_runtime.h>

static inline int idiv(int a, int b) { return (a + b - 1) / b; }

// bijective XCD-chunk swizzle (8 XCDs): contiguous block chunks per XCD
__device__ __forceinline__ int swz8(int bid, int nb) {
    int q = nb >> 3, r = nb & 7;
    int x = bid & 7, c = bid >> 3;
    return (x < r ? x * (q + 1) : r * (q + 1) + (x - r) * q) + c;
}

// ---------------- zero region via kernel ----------------
__global__ void k_zero(float4* __restrict__ p, long n4) {
    long t = (long)blockIdx.x * blockDim.x + threadIdx.x;
    long stride = (long)gridDim.x * blockDim.x;
    for (; t < n4; t += stride) p[t] = make_float4(0.f, 0.f, 0.f, 0.f);
}

// ---- layer1 prep (fused): up-run bounds + smaller-neighbor histogram ----
__global__ void k_prep1(const int* __restrict__ src, const int* __restrict__ dst,
                        int* __restrict__ ust, int* __restrict__ uen,
                        int* __restrict__ cntS, int E) {
    int e = blockIdx.x * blockDim.x + threadIdx.x;
    if (e >= E) return;
    int s = src[e], d = dst[e];
    if (s >= d) return;  // only up-edges
    atomicAdd(&cntS[d], 1);
    bool prevup = false; int ps = -1;
    if (e > 0) { ps = src[e - 1]; prevup = (ps < dst[e - 1]); }
    if (e == 0 || !prevup || ps != s) ust[s] = e;
    bool nextup = false; int ns = -1;
    if (e + 1 < E) { ns = src[e + 1]; nextup = (ns < dst[e + 1]); }
    if (e + 1 == E || !nextup || ns != s) uen[s] = e + 1;
}

// ---- layer2 bounds: src2 globally sorted; runs give full neighbor lists ----
__global__ void k_bounds2(const int* __restrict__ src, int* __restrict__ rs,
                          int* __restrict__ re, int E) {
    int e = blockIdx.x * blockDim.x + threadIdx.x;
    if (e >= E) return;
    int s = src[e];
    if (e == 0 || src[e - 1] != s) rs[s] = e;
    if (e + 1 == E || src[e + 1] != s) re[s] = e + 1;
}

// ---- dinv layer1: deg = cntS + up-run length ----
__global__ void k_dinv1(const int* __restrict__ cntS, const int* __restrict__ ust,
                        const int* __restrict__ uen, float* __restrict__ dinv, int n) {
    int t = blockIdx.x * blockDim.x + threadIdx.x;
    if (t < n) {
        int deg = cntS[t] + uen[t] - ust[t];
        dinv[t] = (deg > 0) ? rsqrtf((float)deg) : 0.0f;
    }
}

// ---- dinv layer2: deg = run length ----
__global__ void k_dinv2(const int* __restrict__ rs, const int* __restrict__ re,
                        float* __restrict__ dinv, int n) {
    int t = blockIdx.x * blockDim.x + threadIdx.x;
    if (t < n) {
        int deg = re[t] - rs[t];
        dinv[t] = (deg > 0) ? rsqrtf((float)deg) : 0.0f;
    }
}

// ---- scan phase 1 ----
__global__ void k_scan_blk(const int* __restrict__ cnt, int* __restrict__ offs,
                           int* __restrict__ blksum, int n) {
    __shared__ int ts[256];
    int blk = blockIdx.x;
    int tid = threadIdx.x;
    int i0 = blk * 1024 + tid * 4;
    int a0 = 0, a1 = 0, a2 = 0, a3 = 0;
    if (i0 + 3 < n) {
        int4 v = *(const int4*)&cnt[i0];
        a0 = v.x; a1 = v.y; a2 = v.z; a3 = v.w;
    } else {
        if (i0 + 0 < n) a0 = cnt[i0 + 0];
        if (i0 + 1 < n) a1 = cnt[i0 + 1];
        if (i0 + 2 < n) a2 = cnt[i0 + 2];
    }
    int tsum = a0 + a1 + a2 + a3;
    ts[tid] = tsum;
    __syncthreads();
    for (int off = 1; off < 256; off <<= 1) {
        int v = (tid >= off) ? ts[tid - off] : 0;
        __syncthreads();
        ts[tid] += v;
        __syncthreads();
    }
    int ex = ts[tid] - tsum;
    if (tid == 255) blksum[blk] = ts[255];
    int p0 = ex, p1 = ex + a0, p2 = p1 + a1, p3 = p2 + a2;
    if (i0 + 3 < n) {
        *(int4*)&offs[i0] = make_int4(p0, p1, p2, p3);
    } else {
        if (i0 + 0 < n) offs[i0 + 0] = p0;
        if (i0 + 1 < n) offs[i0 + 1] = p1;
        if (i0 + 2 < n) offs[i0 + 2] = p2;
    }
}

// ---- scan phase 2 ----
__global__ void k_scan_tot(int* __restrict__ blksum, int nblk) {
    __shared__ int s[1024];
    int tid = threadIdx.x;
    int v = (tid < nblk) ? blksum[tid] : 0;
    s[tid] = v;
    __syncthreads();
    for (int off = 1; off < 1024; off <<= 1) {
        int t = (tid >= off) ? s[tid - off] : 0;
        __syncthreads();
        s[tid] += t;
        __syncthreads();
    }
    if (tid < nblk) blksum[tid] = s[tid] - v;
}

// ---- scan phase 3 ----
__global__ void k_scan_add(int* __restrict__ offs, int* __restrict__ cursor,
                           const int* __restrict__ blksum, int n) {
    int t = blockIdx.x * blockDim.x + threadIdx.x;
    if (t < n) {
        int v = offs[t] + blksum[t >> 10];
        offs[t] = v;
        cursor[t] = v;
    }
}

// ---- fill small-CSR: only up-edges, keyed by larger endpoint ----
__global__ void k_fillS(const int* __restrict__ src, const int* __restrict__ dst,
                        int* __restrict__ cursor, int* __restrict__ csr, int E) {
    int e = blockIdx.x * blockDim.x + threadIdx.x;
    if (e >= E) return;
    int s = src[e], d = dst[e];
    if (s < d) {
        int pos = atomicAdd(&cursor[d], 1);
        csr[pos] = s;
    }
}

// ---- gather1: XCD-swizzled, unroll-4 ----
template <int LOGF>
__global__ void k_gather1(const int* __restrict__ ust, const int* __restrict__ uen,
                          const int* __restrict__ dst1, const int* __restrict__ offsS,
                          const int* __restrict__ cntS, const int* __restrict__ csrS,
                          const float* __restrict__ dinv, const float* __restrict__ xin,
                          float* __restrict__ tx, int n) {
    int vb = swz8(blockIdx.x, gridDim.x);
    int t = vb * blockDim.x + threadIdx.x;
    int d = t >> LOGF, f = t & ((1 << LOGF) - 1);
    if (d >= n) return;
    float acc = 0.0f;
    int e = ust[d], e1 = uen[d];
    for (; e + 3 < e1; e += 4) {
        int s0 = dst1[e], s1 = dst1[e + 1], s2 = dst1[e + 2], s3 = dst1[e + 3];
        float v0 = dinv[s0] * xin[((long)s0 << LOGF) + f];
        float v1 = dinv[s1] * xin[((long)s1 << LOGF) + f];
        float v2 = dinv[s2] * xin[((long)s2 << LOGF) + f];
        float v3 = dinv[s3] * xin[((long)s3 << LOGF) + f];
        acc += (v0 + v1) + (v2 + v3);
    }
    for (; e < e1; e++) {
        int s = dst1[e];
        acc += dinv[s] * xin[((long)s << LOGF) + f];
    }
    int i = offsS[d], i1 = i + cntS[d];
    for (; i + 3 < i1; i += 4) {
        int s0 = csrS[i], s1 = csrS[i + 1], s2 = csrS[i + 2], s3 = csrS[i + 3];
        float v0 = dinv[s0] * xin[((long)s0 << LOGF) + f];
        float v1 = dinv[s1] * xin[((long)s1 << LOGF) + f];
        float v2 = dinv[s2] * xin[((long)s2 << LOGF) + f];
        float v3 = dinv[s3] * xin[((long)s3 << LOGF) + f];
        acc += (v0 + v1) + (v2 + v3);
    }
    for (; i < i1; i++) {
        int s = csrS[i];
        acc += dinv[s] * xin[((long)s << LOGF) + f];
    }
    tx[((long)d << LOGF) + f] = -dinv[d] * acc;
}

// ---- gather2: XCD-swizzled, unroll-4 ----
template <int LOGF>
__global__ void k_gather2(const int* __restrict__ rs, const int* __restrict__ re,
                          const int* __restrict__ dst2, const float* __restrict__ dinv,
                          const float* __restrict__ xin, float* __restrict__ tx, int n) {
    int vb = swz8(blockIdx.x, gridDim.x);
    int t = vb * blockDim.x + threadIdx.x;
    int d = t >> LOGF, f = t & ((1 << LOGF) - 1);
    if (d >= n) return;
    float acc = 0.0f;
    int j = rs[d], j1 = re[d];
    for (; j + 3 < j1; j += 4) {
        int s0 = dst2[j], s1 = dst2[j + 1], s2 = dst2[j + 2], s3 = dst2[j + 3];
        float v0 = dinv[s0] * xin[((long)s0 << LOGF) + f];
        float v1 = dinv[s1] * xin[((long)s1 << LOGF) + f];
        float v2 = dinv[s2] * xin[((long)s2 << LOGF) + f];
        float v3 = dinv[s3] * xin[((long)s3 << LOGF) + f];
        acc += (v0 + v1) + (v2 + v3);
    }
    for (; j < j1; j++) {
        int s = dst2[j];
        acc += dinv[s] * xin[((long)s << LOGF) + f];
    }
    tx[((long)d << LOGF) + f] = -dinv[d] * acc;
}

// ---- layer1 fused: val = relu(x@W0 + tx@W1 + b); hp[cl[n]][j] max= val ----
__global__ void k_cheb1_max(const float* __restrict__ x, const float* __restrict__ tx,
                            const float* __restrict__ W0, const float* __restrict__ W1,
                            const float* __restrict__ b, const int* __restrict__ cl,
                            float* __restrict__ hp, int N) {
    __shared__ float sW0[16 * 32], sW1[16 * 32], sb[32];
    for (int i = threadIdx.x; i < 16 * 32; i += blockDim.x) {
        sW0[i] = W0[i];
        sW1[i] = W1[i];
    }
    if (threadIdx.x < 32) sb[threadIdx.x] = b[threadIdx.x];
    __syncthreads();
    int t = blockIdx.x * blockDim.x + threadIdx.x;
    int n = t >> 5, j = t & 31;
    if (n >= N) return;
    const float* xr = x + (long)n * 16;
    const float* tr = tx + (long)n * 16;
    float acc = sb[j];
#pragma unroll
    for (int k = 0; k < 16; k++) acc += xr[k] * sW0[k * 32 + j] + tr[k] * sW1[k * 32 + j];
    float v = fmaxf(acc, 0.0f);  // >= 0, so int-punned atomicMax on zero-init is exact
    atomicMax((int*)&hp[((long)cl[n] << 5) + j], __float_as_int(v));
}

// ---- layer2 fused: val = relu(hp@W0 + tx@W1 + b); h3[cl[n]][j] max= val ----
__global__ void k_cheb2_max(const float* __restrict__ xp, const float* __restrict__ tx,
                            const float* __restrict__ W0, const float* __restrict__ W1,
                            const float* __restrict__ b, const int* __restrict__ cl,
                            float* __restrict__ h3, int n1) {
    __shared__ float sW0[32 * 64], sW1[32 * 64], sb[64];
    for (int i = threadIdx.x; i < 32 * 64; i += blockDim.x) {
        sW0[i] = W0[i];
        sW1[i] = W1[i];
    }
    if (threadIdx.x < 64) sb[threadIdx.x] = b[threadIdx.x];
    __syncthreads();
    int t = blockIdx.x * blockDim.x + threadIdx.x;
    int n = t >> 6, j = t & 63;
    if (n >= n1) return;
    const float* xr = xp + (long)n * 32;
    const float* tr = tx + (long)n * 32;
    float acc = sb[j];
#pragma unroll
    for (int k = 0; k < 32; k++) acc += xr[k] * sW0[k * 64 + j] + tr[k] * sW1[k * 64 + j];
    float v = fmaxf(acc, 0.0f);
    atomicMax((int*)&h3[((long)cl[n] << 6) + j], __float_as_int(v));
}

// ---- per-graph sum + count: two-stage ----
__global__ void k_gsum(const float* __restrict__ h3, const int* __restrict__ batch,
                       float* __restrict__ gsum, float* __restrict__ gcnt, int n2) {
    __shared__ float s[8 * 64];
    __shared__ float sc[8];
    for (int i = threadIdx.x; i < 512; i += blockDim.x) s[i] = 0.0f;
    if (threadIdx.x < 8) sc[threadIdx.x] = 0.0f;
    __syncthreads();
    long total = (long)n2 * 64;
    long stride = (long)gridDim.x * blockDim.x;
    for (long t = (long)blockIdx.x * blockDim.x + threadIdx.x; t < total; t += stride) {
        int n = (int)(t >> 6), f = (int)(t & 63);
        int g = batch[n];
        atomicAdd(&s[g * 64 + f], h3[t]);
        if (f == 0) atomicAdd(&sc[g], 1.0f);
    }
    __syncthreads();
    for (int i = threadIdx.x; i < 512; i += blockDim.x) atomicAdd(&gsum[i], s[i]);
    if (threadIdx.x < 8) atomicAdd(&gcnt[threadIdx.x], sc[threadIdx.x]);
}

// ---------------- fc1 ----------------
__global__ void k_fc1(const float* __restrict__ gsum, const float* __restrict__ gcnt,
                      const float* __restrict__ fcw1, const float* __restrict__ fcb1,
                      float* __restrict__ g1) {
    __shared__ float sg[8 * 64];
    int tid = threadIdx.x;
    if (tid < 512) {
        float c = gcnt[tid >> 6];
        sg[tid] = (c > 0.0f) ? gsum[tid] / c : 0.0f;
    }
    __syncthreads();
    int gi = tid >> 7, j = tid & 127;
    float acc = fcb1[j];
#pragma unroll 8
    for (int k = 0; k < 64; k++) acc += sg[gi * 64 + k] * fcw1[k * 128 + j];
    g1[tid] = fmaxf(acc, 0.0f);
}

// ---------------- fc2 ----------------
__global__ void k_fc2(const float* __restrict__ g1, const float* __restrict__ fcw2,
                      const float* __restrict__ fcb2, float* __restrict__ out, int OUT) {
    __shared__ float sg[8 * 128];
    for (int i = threadIdx.x; i < 1024; i += blockDim.x) sg[i] = g1[i];
    __syncthreads();
    int o = blockIdx.x * blockDim.x + threadIdx.x;
    if (o >= OUT) return;
    float bias = fcb2[o];
    float acc[8];
#pragma unroll
    for (int gi = 0; gi < 8; gi++) acc[gi] = bias;
    for (int k = 0; k < 128; k++) {
        float w = fcw2[(long)k * OUT + o];
#pragma unroll
        for (int gi = 0; gi < 8; gi++) acc[gi] += sg[gi * 128 + k] * w;
    }
#pragma unroll
    for (int gi = 0; gi < 8; gi++) out[(long)gi * OUT + o] = acc[gi];
}

extern "C" void kernel_launch(void* const* d_in, const int* in_sizes, int n_in,
                              void* d_out, int out_size, void* d_ws, size_t ws_size,
                              hipStream_t stream) {
    const float* x    = (const float*)d_in[0];
    const float* W0a  = (const float*)d_in[1];
    const float* W1a  = (const float*)d_in[2];
    const float* b1   = (const float*)d_in[3];
    const float* W0b  = (const float*)d_in[4];
    const float* W1b  = (const float*)d_in[5];
    const float* b2   = (const float*)d_in[6];
    const float* fcw1 = (const float*)d_in[7];
    const float* fcb1 = (const float*)d_in[8];
    const float* fcw2 = (const float*)d_in[9];
    const float* fcb2 = (const float*)d_in[10];
    const int* ei1    = (const int*)d_in[11];
    const int* cl1    = (const int*)d_in[12];
    const int* ei2    = (const int*)d_in[13];
    const int* cl2    = (const int*)d_in[14];
    const int* b3     = (const int*)d_in[15];

    const int N  = in_sizes[12];        // 80000
    const int E1 = in_sizes[11] / 2;
    const int E2 = in_sizes[13] / 2;
    const int n1 = in_sizes[14];
    const int n2 = in_sizes[15];
    const int G  = 8;
    const int OUT = out_size / G;       // 20000

    const int nmax = (N > n1) ? N : n1;

    // ---- workspace: [zeroed: cntS|ust|uen|rs2|re2|hp|h3|small] [offsS|cursorS|csrS|dinv|blksum|txA]
    auto rnd = [](size_t b) { return (b + 255) & ~(size_t)255; };
    size_t cntB  = rnd((size_t)N * 4);
    size_t ustB  = rnd((size_t)N * 4);
    size_t uenB  = rnd((size_t)N * 4);
    size_t rs2B  = rnd((size_t)n1 * 4);
    size_t re2B  = rnd((size_t)n1 * 4);
    size_t hpB   = rnd((size_t)n1 * 32 * 4);
    size_t h3B   = rnd((size_t)n2 * 64 * 4);
    size_t smlB  = rnd((512 + 8 + 1024) * 4);
    size_t offB  = rnd((size_t)N * 4);
    size_t curB  = rnd((size_t)N * 4);
    size_t csrB  = rnd((size_t)(E1 / 2 + 64) * 4);
    size_t dinvB = rnd((size_t)nmax * 4);
    size_t blkB  = rnd((size_t)1024 * 4);

    char* base = (char*)d_ws;
    char* p = base;
    int*   cntS   = (int*)p;           p += cntB;
    int*   ust    = (int*)p;           p += ustB;
    int*   uen    = (int*)p;           p += uenB;
    int*   rs2    = (int*)p;           p += rs2B;
    int*   re2    = (int*)p;           p += re2B;
    float* hp     = (float*)p;         p += hpB;
    float* h3     = (float*)p;         p += h3B;
    float* gsum   = (float*)p;         p += smlB;
    float* gcnt   = gsum + 512;
    float* g1     = gcnt + 8;
    size_t zeroB  = (size_t)(p - base);
    int*   offsS  = (int*)p;           p += offB;
    int*   cursorS= (int*)p;           p += curB;
    int*   csrS   = (int*)p;           p += csrB;
    float* dinv   = (float*)p;         p += dinvB;
    int*   blksum = (int*)p;           p += blkB;
    float* txA    = (float*)p;
    (void)ws_size;

    dim3 B(256);
    // ---- zero accumulator/bounds regions ----
    {
        long n4 = (long)(zeroB / 16);
        int g = idiv((int)((n4 < 1048576) ? n4 : 1048576), 256);
        if (g < 1) g = 1;
        if (g > 4096) g = 4096;
        k_zero<<<g, B, 0, stream>>>((float4*)base, n4);
    }

    // ---- layer 1 ----
    {
        int nblk = idiv(N, 1024);
        k_prep1<<<idiv(E1, 256), B, 0, stream>>>(ei1, ei1 + E1, ust, uen, cntS, E1);
        k_dinv1<<<idiv(N, 256), B, 0, stream>>>(cntS, ust, uen, dinv, N);
        k_scan_blk<<<nblk, B, 0, stream>>>(cntS, offsS, blksum, N);
        k_scan_tot<<<1, 1024, 0, stream>>>(blksum, nblk);
        k_scan_add<<<idiv(N, 256), B, 0, stream>>>(offsS, cursorS, blksum, N);
        k_fillS<<<idiv(E1, 256), B, 0, stream>>>(ei1, ei1 + E1, cursorS, csrS, E1);
        k_gather1<4><<<idiv(N * 16, 256), B, 0, stream>>>(ust, uen, ei1 + E1, offsS, cntS, csrS,
                                                          dinv, x, txA, N);
        k_cheb1_max<<<idiv(N * 32, 256), B, 0, stream>>>(x, txA, W0a, W1a, b1, cl1, hp, N);
    }

    // ---- layer 2: sorted src2 -> no CSR at all ----
    {
        k_bounds2<<<idiv(E2, 256), B, 0, stream>>>(ei2, rs2, re2, E2);
        k_dinv2<<<idiv(n1, 256), B, 0, stream>>>(rs2, re2, dinv, n1);
        k_gather2<5><<<idiv(n1 * 32, 256), B, 0, stream>>>(rs2, re2, ei2 + E2, dinv, hp, txA, n1);
        k_cheb2_max<<<idiv(n1 * 64, 256), B, 0, stream>>>(hp, txA, W0b, W1b, b2, cl2, h3, n1);
    }

    // ---- readout ----
    int gb = idiv(n2 * 64, 256);
    if (gb > 256) gb = 256;
    k_gsum<<<gb, B, 0, stream>>>(h3, b3, gsum, gcnt, n2);
    k_fc1<<<1, 1024, 0, stream>>>(gsum, gcnt, fcw1, fcb1, g1);
    k_fc2<<<idiv(OUT, 256), B, 0, stream>>>(g1, fcw2, fcb2, (float*)d_out, OUT);
}